// Round 3
// baseline (960.375 us; speedup 1.0000x reference)
//
#include <hip/hip_runtime.h>

// GCN 2-layer forward on MI355X — bucket-sorted edges + LDS accumulators.
// N=150000, E=1.2M, IN=HID=64, layer-2 out dim = 1.
//
// pre1 = dinv[v]*(sum_{e:dst=v} Y[src] + Y[v]) + b1,  Y = (x@W1) row-scaled by dinv
// zs   = (relu(pre1).W2) * dinv
// out  = relu(dinv[v]*(sum zs[src] + zs[v]) + b2), sliced v%15 in 3..14
//
// Edges are bucketed by dst>>8 (one pass, clustered writes). Each bucket's
// 256 dst nodes fit a 64KB LDS accumulator -> no per-node CSR, no scans.

#define BK 256  // nodes per bucket

__global__ __launch_bounds__(256) void k_deg(const int* __restrict__ dst, int E, int* __restrict__ deg) {
    int e = blockIdx.x * 256 + threadIdx.x;
    if (e < E) atomicAdd(&deg[dst[e]], 1);
}

// per-bucket: dinv[v] = rsqrt(deg+1); bcnt[b] = sum deg over bucket
__global__ __launch_bounds__(256) void k_degsum(const int* __restrict__ deg, int N,
                                                float* __restrict__ dinv, int* __restrict__ bcnt) {
    __shared__ int s[256];
    int v = blockIdx.x * 256 + threadIdx.x;
    int d = (v < N) ? deg[v] : 0;
    if (v < N) dinv[v] = rsqrtf((float)d + 1.0f);
    s[threadIdx.x] = d;
    __syncthreads();
    for (int o = 128; o > 0; o >>= 1) {
        if (threadIdx.x < o) s[threadIdx.x] += s[threadIdx.x + o];
        __syncthreads();
    }
    if (threadIdx.x == 0) bcnt[blockIdx.x] = s[0];
}

// single block: exclusive scan of bcnt[NB] -> bbase[NB+1]; bcur = bbase
__global__ __launch_bounds__(1024) void k_bscan(const int* __restrict__ bcnt, int nb,
                                                int* __restrict__ bbase, int* __restrict__ bcur) {
    __shared__ int s[1024];
    int t = threadIdx.x;
    int v = (t < nb) ? bcnt[t] : 0;
    s[t] = v;
    __syncthreads();
    for (int o = 1; o < 1024; o <<= 1) {
        int x = s[t];
        if (t >= o) x += s[t - o];
        __syncthreads();
        s[t] = x;
        __syncthreads();
    }
    if (t < nb) {
        int ex = s[t] - v;
        bbase[t] = ex;
        bcur[t] = ex;
        if (t == nb - 1) bbase[nb] = s[t];
    }
}

// bucket scatter: ebuf[p] = (dst&255)<<24 | src   (writes cluster per-bucket)
__global__ __launch_bounds__(256) void k_bucket(const int* __restrict__ src, const int* __restrict__ dst,
                                                int E, int* __restrict__ bcur, unsigned* __restrict__ ebuf) {
    int e = blockIdx.x * 256 + threadIdx.x;
    if (e >= E) return;
    int d = dst[e];
    int p = atomicAdd(&bcur[d >> 8], 1);
    ebuf[p] = ((unsigned)(d & 255) << 24) | (unsigned)src[e];
}

// X[N,64] @ W[64,64], row-scale by dinv -> Y
__global__ __launch_bounds__(256) void k_gemm1(const float* __restrict__ X, const float* __restrict__ W,
                                               const float* __restrict__ dinv, int N,
                                               float* __restrict__ Y) {
    __shared__ float Wl[64 * 64];
    __shared__ float Al[64 * 66];
    const int t = threadIdx.x;
    const int row0 = blockIdx.x * 64;
    {
        const float4* Wv = (const float4*)W;
        float4* Wlv = (float4*)Wl;
#pragma unroll
        for (int i = 0; i < 4; i++) Wlv[t + i * 256] = Wv[t + i * 256];
    }
    {
#pragma unroll
        for (int i = 0; i < 4; i++) {
            int f = t + i * 256;
            int r = f >> 4;
            int c4 = f & 15;
            int gr = row0 + r;
            float4 v = (gr < N) ? ((const float4*)X)[gr * 16 + c4] : make_float4(0.f, 0.f, 0.f, 0.f);
            float* dp = &Al[r * 66 + c4 * 4];
            dp[0] = v.x; dp[1] = v.y; dp[2] = v.z; dp[3] = v.w;
        }
    }
    __syncthreads();

    const int r = t & 63;
    const int cb = t >> 6;
    float acc[16];
#pragma unroll
    for (int j = 0; j < 16; j++) acc[j] = 0.f;
#pragma unroll 8
    for (int k = 0; k < 64; k++) {
        float a = Al[r * 66 + k];
#pragma unroll
        for (int j = 0; j < 16; j++)
            acc[j] = fmaf(a, Wl[k * 64 + cb * 16 + j], acc[j]);
    }
    int gr = row0 + r;
    if (gr < N) {
        float s = dinv[gr];
#pragma unroll
        for (int j = 0; j < 16; j += 4)
            ((float4*)(Y + (size_t)gr * 64 + cb * 16))[j >> 2] =
                make_float4(acc[j] * s, acc[j + 1] * s, acc[j + 2] * s, acc[j + 3] * s);
    }
}

// per-bucket layer-1 aggregate in LDS + fused epilogue -> zs
__global__ __launch_bounds__(256) void k_agg3(const float* __restrict__ Y, const unsigned* __restrict__ ebuf,
                                              const int* __restrict__ bbase, const float* __restrict__ dinv,
                                              const float* __restrict__ b1, const float* __restrict__ W2,
                                              int N, float* __restrict__ zs) {
    __shared__ float acc[BK * 64];  // 64 KB
    const int b = blockIdx.x;
    const int v0 = b << 8;
    const int nv = min(BK, N - v0);
    const int t = threadIdx.x;
    const int li = t & 15;   // feature float4 slot
    const int g = t >> 4;    // group 0..15

    const float4* Y4 = (const float4*)Y;
    // init: acc[node] = Y[v0+node] (self-loop term)
#pragma unroll
    for (int n = 0; n < 16; n++) {
        int node = g + 16 * n;
        if (node < nv) {
            float4 v = Y4[(size_t)(v0 + node) * 16 + li];
            float* dp = &acc[node * 64 + li * 4];
            dp[0] = v.x; dp[1] = v.y; dp[2] = v.z; dp[3] = v.w;
        }
    }
    __syncthreads();

    const int bb = bbase[b];
    const int be = bbase[b + 1];
    // edge loop: 16 groups, unroll 2 (32 edges in flight per block)
    for (int j = bb + g; j < be; j += 32) {
        unsigned e0 = ebuf[j];
        int j2 = j + 16;
        bool has1 = (j2 < be);
        unsigned e1 = has1 ? ebuf[j2] : 0u;
        int s0 = e0 & 0xFFFFFF, d0 = e0 >> 24;
        float4 m0 = Y4[(size_t)s0 * 16 + li];
        float4 m1 = make_float4(0.f, 0.f, 0.f, 0.f);
        int s1 = e1 & 0xFFFFFF, d1 = e1 >> 24;
        if (has1) m1 = Y4[(size_t)s1 * 16 + li];
        float* a0 = &acc[d0 * 64 + li * 4];
        atomicAdd(a0 + 0, m0.x); atomicAdd(a0 + 1, m0.y);
        atomicAdd(a0 + 2, m0.z); atomicAdd(a0 + 3, m0.w);
        if (has1) {
            float* a1 = &acc[d1 * 64 + li * 4];
            atomicAdd(a1 + 0, m1.x); atomicAdd(a1 + 1, m1.y);
            atomicAdd(a1 + 2, m1.z); atomicAdd(a1 + 3, m1.w);
        }
    }
    __syncthreads();

    // epilogue: h1 = relu(dinv*acc + b1); zs = (h1.W2)*dinv
    float4 bb4 = ((const float4*)b1)[li];
    float4 w4 = ((const float4*)W2)[li];
#pragma unroll
    for (int n = 0; n < 16; n++) {
        int node = g + 16 * n;
        if (node < nv) {
            const float* ap = &acc[node * 64 + li * 4];
            float dv = dinv[v0 + node];
            float h0 = fmaxf(fmaf(dv, ap[0], bb4.x), 0.f);
            float h1 = fmaxf(fmaf(dv, ap[1], bb4.y), 0.f);
            float h2 = fmaxf(fmaf(dv, ap[2], bb4.z), 0.f);
            float h3 = fmaxf(fmaf(dv, ap[3], bb4.w), 0.f);
            float p = h0 * w4.x + h1 * w4.y + h2 * w4.z + h3 * w4.w;
            p += __shfl_xor(p, 1);
            p += __shfl_xor(p, 2);
            p += __shfl_xor(p, 4);
            p += __shfl_xor(p, 8);
            if (li == 0) zs[v0 + node] = p * dv;
        }
    }
}

// per-bucket layer-2 scalar aggregate + output slice
__global__ __launch_bounds__(256) void k_out3(const float* __restrict__ zs, const unsigned* __restrict__ ebuf,
                                              const int* __restrict__ bbase, const float* __restrict__ dinv,
                                              const float* __restrict__ b2, int N, float* __restrict__ out) {
    __shared__ float sacc[BK];
    const int b = blockIdx.x;
    const int v0 = b << 8;
    const int nv = min(BK, N - v0);
    const int t = threadIdx.x;

    if (t < nv) sacc[t] = zs[v0 + t];  // self-loop
    __syncthreads();

    const int bb = bbase[b];
    const int be = bbase[b + 1];
    for (int j = bb + t; j < be; j += 256) {
        unsigned e = ebuf[j];
        atomicAdd(&sacc[e >> 24], zs[e & 0xFFFFFF]);
    }
    __syncthreads();

    if (t < nv) {
        int v = v0 + t;
        int q = v / 15;
        int r = v - q * 15;
        if (r >= 3) {
            float tv = fmaf(dinv[v], sacc[t], b2[0]);
            out[q * 12 + (r - 3)] = fmaxf(tv, 0.f);
        }
    }
}

extern "C" void kernel_launch(void* const* d_in, const int* in_sizes, int n_in,
                              void* d_out, int out_size, void* d_ws, size_t ws_size,
                              hipStream_t stream) {
    const float* obs = (const float*)d_in[0];
    const int*   ei  = (const int*)d_in[1];   // [2,E]; JAX x64-off -> int32
    const float* W1  = (const float*)d_in[2];
    const float* b1  = (const float*)d_in[3];
    const float* W2  = (const float*)d_in[4];
    const float* b2  = (const float*)d_in[5];

    const int N = in_sizes[0] / 64;
    const int E = in_sizes[1] / 2;
    const int NB = (N + BK - 1) / BK;       // 586

    const int* src = ei;
    const int* dst = ei + E;

    // workspace layout
    float*    Y     = (float*)d_ws;            // N*64 floats (38.4 MB)
    float*    dinv  = Y + (size_t)N * 64;      // N
    float*    zs    = dinv + N;                // N
    int*      deg   = (int*)(zs + N);          // N
    int*      bcnt  = deg + N;                 // NB
    int*      bbase = bcnt + NB;               // NB+1
    int*      bcur  = bbase + NB + 1;          // NB
    unsigned* ebuf  = (unsigned*)(bcur + NB);  // E (4.8 MB)

    hipMemsetAsync(deg, 0, (size_t)N * sizeof(int), stream);

    k_deg   <<<(E + 255) / 256, 256, 0, stream>>>(dst, E, deg);
    k_degsum<<<NB, 256, 0, stream>>>(deg, N, dinv, bcnt);
    k_bscan <<<1, 1024, 0, stream>>>(bcnt, NB, bbase, bcur);
    k_gemm1 <<<(N + 63) / 64, 256, 0, stream>>>(obs, W1, dinv, N, Y);
    k_bucket<<<(E + 255) / 256, 256, 0, stream>>>(src, dst, E, bcur, ebuf);
    k_agg3  <<<NB, 256, 0, stream>>>(Y, ebuf, bbase, dinv, b1, W2, N, zs);
    k_out3  <<<NB, 256, 0, stream>>>(zs, ebuf, bbase, dinv, b2, N, (float*)d_out);
}

// Round 4
// 507.015 us; speedup vs baseline: 1.8942x; 1.8942x over previous
//
#include <hip/hip_runtime.h>

// GCN 2-layer forward on MI355X — CSR gather (per-node, high TLP) with
// bucket-clustered CSR build and bf16 message matrix.
// N=150000, E=1.2M, IN=HID=64, layer-2 out dim = 1.
//
// pre1 = dinv[v]*(sum_{e:dst=v} Y[src] + Y[v]) + b1,  Y = (x@W1) row-scaled by dinv (bf16)
// zs   = (relu(pre1).W2) * dinv
// out  = relu(dinv[v]*(sum zs[src] + zs[v]) + b2), sliced v%15 in 3..14

#define BK 256  // nodes per bucket (bucket b covers nodes [b*256, b*256+256))

typedef unsigned int uint;
typedef unsigned short ushort;

static __device__ __forceinline__ ushort f2bf(float x) {
    uint u = __float_as_uint(x);
    u = (u + 0x7FFFu + ((u >> 16) & 1u)) >> 16;   // RN-even
    return (ushort)u;
}

static __device__ __forceinline__ float4 bf4(uint2 p) {
    float4 r;
    r.x = __uint_as_float(p.x << 16);
    r.y = __uint_as_float(p.x & 0xFFFF0000u);
    r.z = __uint_as_float(p.y << 16);
    r.w = __uint_as_float(p.y & 0xFFFF0000u);
    return r;
}

__global__ __launch_bounds__(256) void k_deg(const int* __restrict__ dst, int E, int* __restrict__ deg) {
    int e = blockIdx.x * 256 + threadIdx.x;
    if (e < E) atomicAdd(&deg[dst[e]], 1);
}

// dinv[v] = rsqrt(deg+1); bcnt[b] = sum of deg over bucket b
__global__ __launch_bounds__(256) void k_degsum(const int* __restrict__ deg, int N,
                                                float* __restrict__ dinv, int* __restrict__ bcnt) {
    __shared__ int s[256];
    int v = blockIdx.x * 256 + threadIdx.x;
    int d = (v < N) ? deg[v] : 0;
    if (v < N) dinv[v] = rsqrtf((float)d + 1.0f);
    s[threadIdx.x] = d;
    __syncthreads();
    for (int o = 128; o > 0; o >>= 1) {
        if (threadIdx.x < o) s[threadIdx.x] += s[threadIdx.x + o];
        __syncthreads();
    }
    if (threadIdx.x == 0) bcnt[blockIdx.x] = s[0];
}

// single block: exclusive scan bcnt[nb] -> boff[nb+1]; bcur = boff
__global__ __launch_bounds__(1024) void k_bscan(const int* __restrict__ bcnt, int nb,
                                                int* __restrict__ boff, int* __restrict__ bcur) {
    __shared__ int s[1024];
    int t = threadIdx.x;
    int v = (t < nb) ? bcnt[t] : 0;
    s[t] = v;
    __syncthreads();
    for (int o = 1; o < 1024; o <<= 1) {
        int x = s[t];
        if (t >= o) x += s[t - o];
        __syncthreads();
        s[t] = x;
        __syncthreads();
    }
    if (t < nb) {
        int ex = s[t] - v;
        boff[t] = ex;
        bcur[t] = ex;
        if (t == nb - 1) boff[nb] = s[t];
    }
}

// rowptr[i] = boff[bucket] + exclusive-prefix of deg within bucket
__global__ __launch_bounds__(256) void k_scan3(const int* __restrict__ deg, const int* __restrict__ boff,
                                               int N, int* __restrict__ rowptr) {
    __shared__ int s[256];
    int i = blockIdx.x * 256 + threadIdx.x;
    int v = (i < N) ? deg[i] : 0;
    s[threadIdx.x] = v;
    __syncthreads();
    for (int o = 1; o < 256; o <<= 1) {
        int x = s[threadIdx.x];
        if (threadIdx.x >= o) x += s[threadIdx.x - o];
        __syncthreads();
        s[threadIdx.x] = x;
        __syncthreads();
    }
    if (i < N) rowptr[i] = s[threadIdx.x] - v + boff[blockIdx.x];
}

// phase 1: bucket edges by dst>>8; winners write consecutive addresses
__global__ __launch_bounds__(256) void k_bucket(const int* __restrict__ src, const int* __restrict__ dst,
                                                int E, int* __restrict__ bcur, uint* __restrict__ ebuf) {
    int e = blockIdx.x * 256 + threadIdx.x;
    if (e >= E) return;
    int d = dst[e];
    int p = atomicAdd(&bcur[d >> 8], 1);
    ebuf[p] = ((uint)(d & 255) << 24) | (uint)src[e];
}

// phase 2: within each bucket place edges at exact CSR slots (8KB write window)
__global__ __launch_bounds__(256) void k_fill2(const uint* __restrict__ ebuf, const int* __restrict__ boff,
                                               const int* __restrict__ rowptr, int N,
                                               int* __restrict__ csrc) {
    __shared__ int cur[BK];
    const int b = blockIdx.x;
    const int v0 = b << 8;
    const int nv = min(BK, N - v0);
    const int t = threadIdx.x;
    if (t < nv) cur[t] = rowptr[v0 + t];
    __syncthreads();
    const int bb = boff[b];
    const int be = boff[b + 1];
    for (int j = bb + t; j < be; j += 256) {
        uint e = ebuf[j];
        int p = atomicAdd(&cur[e >> 24], 1);
        csrc[p] = (int)(e & 0xFFFFFFu);
    }
}

// X[N,64] @ W[64,64], row-scale by dinv -> Y (bf16)
__global__ __launch_bounds__(256) void k_gemm1(const float* __restrict__ X, const float* __restrict__ W,
                                               const float* __restrict__ dinv, int N,
                                               ushort* __restrict__ Yh) {
    __shared__ float Wl[64 * 64];
    __shared__ float Al[64 * 66];
    const int t = threadIdx.x;
    const int row0 = blockIdx.x * 64;
    {
        const float4* Wv = (const float4*)W;
        float4* Wlv = (float4*)Wl;
#pragma unroll
        for (int i = 0; i < 4; i++) Wlv[t + i * 256] = Wv[t + i * 256];
    }
    {
#pragma unroll
        for (int i = 0; i < 4; i++) {
            int f = t + i * 256;
            int r = f >> 4;
            int c4 = f & 15;
            int gr = row0 + r;
            float4 v = (gr < N) ? ((const float4*)X)[gr * 16 + c4] : make_float4(0.f, 0.f, 0.f, 0.f);
            float* dp = &Al[r * 66 + c4 * 4];
            dp[0] = v.x; dp[1] = v.y; dp[2] = v.z; dp[3] = v.w;
        }
    }
    __syncthreads();

    const int r = t & 63;
    const int cb = t >> 6;
    float acc[16];
#pragma unroll
    for (int j = 0; j < 16; j++) acc[j] = 0.f;
#pragma unroll 8
    for (int k = 0; k < 64; k++) {
        float a = Al[r * 66 + k];
#pragma unroll
        for (int j = 0; j < 16; j++)
            acc[j] = fmaf(a, Wl[k * 64 + cb * 16 + j], acc[j]);
    }
    int gr = row0 + r;
    if (gr < N) {
        float s = dinv[gr];
        ushort* op = Yh + (size_t)gr * 64 + cb * 16;
#pragma unroll
        for (int j = 0; j < 16; j += 4) {
            ushort4 o = make_ushort4(f2bf(acc[j] * s), f2bf(acc[j + 1] * s),
                                     f2bf(acc[j + 2] * s), f2bf(acc[j + 3] * s));
            ((ushort4*)(op + j))[0] = o;
        }
    }
}

// Fused layer-1 gather (bf16 rows) + bias/relu + dot(W2) + *dinv -> zs
// 16 lanes per node; lane li owns features 4li..4li+3 (one uint2 = 4 bf16).
__global__ __launch_bounds__(256) void k_agg(const ushort* __restrict__ Yh, const int* __restrict__ rowptr,
                                             const int* __restrict__ deg, const int* __restrict__ csrc,
                                             const float* __restrict__ dinv, const float* __restrict__ b1,
                                             const float* __restrict__ W2, int N, float* __restrict__ zs) {
    int t = blockIdx.x * 256 + threadIdx.x;
    int v = t >> 4;
    if (v >= N) return;
    int li = t & 15;
    const uint2* Y2 = (const uint2*)Yh;
    int start = rowptr[v];
    int cnt = deg[v];
    float4 acc = bf4(Y2[(size_t)v * 16 + li]);  // self-loop term
    for (int j = 0; j < cnt; j++) {
        int s = csrc[start + j];                 // broadcast across the 16 lanes
        float4 m = bf4(Y2[(size_t)s * 16 + li]); // 128B row, coalesced
        acc.x += m.x; acc.y += m.y; acc.z += m.z; acc.w += m.w;
    }
    float dv = dinv[v];
    float4 bb = ((const float4*)b1)[li];
    float4 w  = ((const float4*)W2)[li];
    float h0 = fmaxf(fmaf(dv, acc.x, bb.x), 0.f);
    float h1 = fmaxf(fmaf(dv, acc.y, bb.y), 0.f);
    float h2 = fmaxf(fmaf(dv, acc.z, bb.z), 0.f);
    float h3 = fmaxf(fmaf(dv, acc.w, bb.w), 0.f);
    float p = h0 * w.x + h1 * w.y + h2 * w.z + h3 * w.w;
    p += __shfl_xor(p, 1);
    p += __shfl_xor(p, 2);
    p += __shfl_xor(p, 4);
    p += __shfl_xor(p, 8);
    if (li == 0) zs[v] = p * dv;
}

// layer-2 scalar gather + output slice: v = (i/12)*15 + 3 + i%12
__global__ __launch_bounds__(256) void k_out2(const float* __restrict__ zs, const int* __restrict__ rowptr,
                                              const int* __restrict__ deg, const int* __restrict__ csrc,
                                              const float* __restrict__ dinv, const float* __restrict__ b2,
                                              int M, float* __restrict__ out) {
    int i = blockIdx.x * 256 + threadIdx.x;
    if (i >= M) return;
    int q = i / 12;
    int c = i - q * 12;
    int v = q * 15 + 3 + c;
    int start = rowptr[v];
    int cnt = deg[v];
    float s = zs[v];
    for (int j = 0; j < cnt; j++) s += zs[csrc[start + j]];  // zs 600KB -> L2 hits
    out[i] = fmaxf(fmaf(dinv[v], s, b2[0]), 0.f);
}

extern "C" void kernel_launch(void* const* d_in, const int* in_sizes, int n_in,
                              void* d_out, int out_size, void* d_ws, size_t ws_size,
                              hipStream_t stream) {
    const float* obs = (const float*)d_in[0];
    const int*   ei  = (const int*)d_in[1];   // [2,E]; JAX x64-off -> int32
    const float* W1  = (const float*)d_in[2];
    const float* b1  = (const float*)d_in[3];
    const float* W2  = (const float*)d_in[4];
    const float* b2  = (const float*)d_in[5];

    const int N = in_sizes[0] / 64;
    const int E = in_sizes[1] / 2;
    const int M = out_size;
    const int NB = (N + BK - 1) / BK;        // 586

    const int* src = ei;
    const int* dst = ei + E;

    // workspace layout
    ushort* Yh    = (ushort*)d_ws;             // N*64 bf16 (19.2 MB)
    float*  dinv  = (float*)(Yh + (size_t)N * 64);
    float*  zs    = dinv + N;
    int*    deg   = (int*)(zs + N);
    int*    rowptr= deg + N;
    int*    bcnt  = rowptr + N;                // NB
    int*    boff  = bcnt + NB;                 // NB+1
    int*    bcur  = boff + NB + 1;             // NB
    uint*   ebuf  = (uint*)(bcur + NB);        // E (4.8 MB)
    int*    csrc  = (int*)(ebuf + E);          // E (4.8 MB)

    hipMemsetAsync(deg, 0, (size_t)N * sizeof(int), stream);

    k_deg   <<<(E + 255) / 256, 256, 0, stream>>>(dst, E, deg);
    k_degsum<<<NB, 256, 0, stream>>>(deg, N, dinv, bcnt);
    k_bscan <<<1, 1024, 0, stream>>>(bcnt, NB, boff, bcur);
    k_scan3 <<<NB, 256, 0, stream>>>(deg, boff, N, rowptr);
    k_bucket<<<(E + 255) / 256, 256, 0, stream>>>(src, dst, E, bcur, ebuf);
    k_gemm1 <<<(N + 63) / 64, 256, 0, stream>>>(obs, W1, dinv, N, Yh);
    k_fill2 <<<NB, 256, 0, stream>>>(ebuf, boff, rowptr, N, csrc);
    k_agg   <<<((size_t)N * 16 + 255) / 256, 256, 0, stream>>>(Yh, rowptr, deg, csrc, dinv, b1, W2, N, zs);
    k_out2  <<<(M + 255) / 256, 256, 0, stream>>>(zs, rowptr, deg, csrc, dinv, b2, M, (float*)d_out);
}

// Round 5
// 202.610 us; speedup vs baseline: 4.7400x; 2.5024x over previous
//
#include <hip/hip_runtime.h>

// GCN 2-layer forward on MI355X — CSR gather with chunked bucket sort.
// N=150000, E=1.2M, IN=HID=64, layer-2 out dim = 1.
//
// pre1 = dinv[v]*(sum_{e:dst=v} Y[src] + Y[v]) + b1,  Y = (x@W1) row-scaled by dinv (bf16)
// zs   = (relu(pre1).W2) * dinv
// out  = relu(dinv[v]*(sum zs[src] + zs[v]) + b2), sliced v%15 in 3..14

#define BK 256        // nodes per bucket
#define NBMAX 640     // >= NB=586
#define EPB 8192      // edges per block in k_bucket2 (32 per thread)

typedef unsigned int uint;
typedef unsigned short ushort;

static __device__ __forceinline__ ushort f2bf(float x) {
    uint u = __float_as_uint(x);
    u = (u + 0x7FFFu + ((u >> 16) & 1u)) >> 16;   // RN-even
    return (ushort)u;
}

static __device__ __forceinline__ float4 bf4(uint2 p) {
    float4 r;
    r.x = __uint_as_float(p.x << 16);
    r.y = __uint_as_float(p.x & 0xFFFF0000u);
    r.z = __uint_as_float(p.y << 16);
    r.w = __uint_as_float(p.y & 0xFFFF0000u);
    return r;
}

__global__ __launch_bounds__(256) void k_deg(const int* __restrict__ dst, int E, int* __restrict__ deg) {
    int e = blockIdx.x * 256 + threadIdx.x;
    if (e < E) atomicAdd(&deg[dst[e]], 1);
}

// dinv[v] = rsqrt(deg+1); bcnt[b] = sum of deg over bucket b
__global__ __launch_bounds__(256) void k_degsum(const int* __restrict__ deg, int N,
                                                float* __restrict__ dinv, int* __restrict__ bcnt) {
    __shared__ int s[256];
    int v = blockIdx.x * 256 + threadIdx.x;
    int d = (v < N) ? deg[v] : 0;
    if (v < N) dinv[v] = rsqrtf((float)d + 1.0f);
    s[threadIdx.x] = d;
    __syncthreads();
    for (int o = 128; o > 0; o >>= 1) {
        if (threadIdx.x < o) s[threadIdx.x] += s[threadIdx.x + o];
        __syncthreads();
    }
    if (threadIdx.x == 0) bcnt[blockIdx.x] = s[0];
}

// single block: exclusive scan bcnt[nb] -> boff[nb+1]; bcur = boff
__global__ __launch_bounds__(1024) void k_bscan(const int* __restrict__ bcnt, int nb,
                                                int* __restrict__ boff, int* __restrict__ bcur) {
    __shared__ int s[1024];
    int t = threadIdx.x;
    int v = (t < nb) ? bcnt[t] : 0;
    s[t] = v;
    __syncthreads();
    for (int o = 1; o < 1024; o <<= 1) {
        int x = s[t];
        if (t >= o) x += s[t - o];
        __syncthreads();
        s[t] = x;
        __syncthreads();
    }
    if (t < nb) {
        int ex = s[t] - v;
        boff[t] = ex;
        bcur[t] = ex;
        if (t == nb - 1) boff[nb] = s[t];
    }
}

// rowptr[i] = boff[bucket] + exclusive prefix of deg within bucket
__global__ __launch_bounds__(256) void k_scan3(const int* __restrict__ deg, const int* __restrict__ boff,
                                               int N, int* __restrict__ rowptr) {
    __shared__ int s[256];
    int i = blockIdx.x * 256 + threadIdx.x;
    int v = (i < N) ? deg[i] : 0;
    s[threadIdx.x] = v;
    __syncthreads();
    for (int o = 1; o < 256; o <<= 1) {
        int x = s[threadIdx.x];
        if (threadIdx.x >= o) x += s[threadIdx.x - o];
        __syncthreads();
        s[threadIdx.x] = x;
        __syncthreads();
    }
    if (i < N) rowptr[i] = s[threadIdx.x] - v + boff[blockIdx.x];
}

// Chunked bucket sort: per-block LDS histogram -> one global atomic per
// (block,bucket) chunk reservation -> LDS-cursor placement (clustered writes).
__global__ __launch_bounds__(256) void k_bucket2(const int* __restrict__ src, const int* __restrict__ dst,
                                                 int E, int nb, int* __restrict__ bcur,
                                                 uint* __restrict__ ebuf) {
    __shared__ int lcnt[NBMAX];
    __shared__ int lbase[NBMAX];
    const int t = threadIdx.x;
    const int e0 = blockIdx.x * EPB;
    const int e1 = min(e0 + EPB, E);

    for (int b = t; b < nb; b += 256) lcnt[b] = 0;
    __syncthreads();

    // phase 1: local histogram of bucket ids
    for (int e = e0 + t; e < e1; e += 256)
        atomicAdd(&lcnt[dst[e] >> 8], 1);
    __syncthreads();

    // phase 2: reserve global chunks, reset local cursors
    for (int b = t; b < nb; b += 256) {
        int c = lcnt[b];
        lbase[b] = (c > 0) ? atomicAdd(&bcur[b], c) : 0;
        lcnt[b] = 0;
    }
    __syncthreads();

    // phase 3: place edges into reserved chunks (consecutive within chunk)
    for (int e = e0 + t; e < e1; e += 256) {
        int d = dst[e];
        int b = d >> 8;
        int p = lbase[b] + atomicAdd(&lcnt[b], 1);
        ebuf[p] = ((uint)(d & 255) << 24) | (uint)src[e];
    }
}

// within each bucket place edges at exact CSR slots (8KB write window)
__global__ __launch_bounds__(256) void k_fill2(const uint* __restrict__ ebuf, const int* __restrict__ boff,
                                               const int* __restrict__ rowptr, int N,
                                               int* __restrict__ csrc) {
    __shared__ int cur[BK];
    const int b = blockIdx.x;
    const int v0 = b << 8;
    const int nv = min(BK, N - v0);
    const int t = threadIdx.x;
    if (t < nv) cur[t] = rowptr[v0 + t];
    __syncthreads();
    const int bb = boff[b];
    const int be = boff[b + 1];
    for (int j = bb + t; j < be; j += 256) {
        uint e = ebuf[j];
        int p = atomicAdd(&cur[e >> 24], 1);
        csrc[p] = (int)(e & 0xFFFFFFu);
    }
}

// X[N,64] @ W[64,64], row-scale by dinv -> Y (bf16)
__global__ __launch_bounds__(256) void k_gemm1(const float* __restrict__ X, const float* __restrict__ W,
                                               const float* __restrict__ dinv, int N,
                                               ushort* __restrict__ Yh) {
    __shared__ float Wl[64 * 64];
    __shared__ float Al[64 * 66];
    const int t = threadIdx.x;
    const int row0 = blockIdx.x * 64;
    {
        const float4* Wv = (const float4*)W;
        float4* Wlv = (float4*)Wl;
#pragma unroll
        for (int i = 0; i < 4; i++) Wlv[t + i * 256] = Wv[t + i * 256];
    }
    {
#pragma unroll
        for (int i = 0; i < 4; i++) {
            int f = t + i * 256;
            int r = f >> 4;
            int c4 = f & 15;
            int gr = row0 + r;
            float4 v = (gr < N) ? ((const float4*)X)[gr * 16 + c4] : make_float4(0.f, 0.f, 0.f, 0.f);
            float* dp = &Al[r * 66 + c4 * 4];
            dp[0] = v.x; dp[1] = v.y; dp[2] = v.z; dp[3] = v.w;
        }
    }
    __syncthreads();

    const int r = t & 63;
    const int cb = t >> 6;
    float acc[16];
#pragma unroll
    for (int j = 0; j < 16; j++) acc[j] = 0.f;
#pragma unroll 8
    for (int k = 0; k < 64; k++) {
        float a = Al[r * 66 + k];
#pragma unroll
        for (int j = 0; j < 16; j++)
            acc[j] = fmaf(a, Wl[k * 64 + cb * 16 + j], acc[j]);
    }
    int gr = row0 + r;
    if (gr < N) {
        float s = dinv[gr];
        ushort* op = Yh + (size_t)gr * 64 + cb * 16;
#pragma unroll
        for (int j = 0; j < 16; j += 4) {
            ushort4 o = make_ushort4(f2bf(acc[j] * s), f2bf(acc[j + 1] * s),
                                     f2bf(acc[j + 2] * s), f2bf(acc[j + 3] * s));
            ((ushort4*)(op + j))[0] = o;
        }
    }
}

// Fused layer-1 gather (bf16 rows) + bias/relu + dot(W2) + *dinv -> zs
__global__ __launch_bounds__(256) void k_agg(const ushort* __restrict__ Yh, const int* __restrict__ rowptr,
                                             const int* __restrict__ deg, const int* __restrict__ csrc,
                                             const float* __restrict__ dinv, const float* __restrict__ b1,
                                             const float* __restrict__ W2, int N, float* __restrict__ zs) {
    int t = blockIdx.x * 256 + threadIdx.x;
    int v = t >> 4;
    if (v >= N) return;
    int li = t & 15;
    const uint2* Y2 = (const uint2*)Yh;
    int start = rowptr[v];
    int cnt = deg[v];
    float4 acc = bf4(Y2[(size_t)v * 16 + li]);  // self-loop term
    for (int j = 0; j < cnt; j++) {
        int s = csrc[start + j];                 // broadcast across the 16 lanes
        float4 m = bf4(Y2[(size_t)s * 16 + li]); // 128B row, coalesced
        acc.x += m.x; acc.y += m.y; acc.z += m.z; acc.w += m.w;
    }
    float dv = dinv[v];
    float4 bb = ((const float4*)b1)[li];
    float4 w  = ((const float4*)W2)[li];
    float h0 = fmaxf(fmaf(dv, acc.x, bb.x), 0.f);
    float h1 = fmaxf(fmaf(dv, acc.y, bb.y), 0.f);
    float h2 = fmaxf(fmaf(dv, acc.z, bb.z), 0.f);
    float h3 = fmaxf(fmaf(dv, acc.w, bb.w), 0.f);
    float p = h0 * w.x + h1 * w.y + h2 * w.z + h3 * w.w;
    p += __shfl_xor(p, 1);
    p += __shfl_xor(p, 2);
    p += __shfl_xor(p, 4);
    p += __shfl_xor(p, 8);
    if (li == 0) zs[v] = p * dv;
}

// layer-2 scalar gather + output slice: v = (i/12)*15 + 3 + i%12
__global__ __launch_bounds__(256) void k_out2(const float* __restrict__ zs, const int* __restrict__ rowptr,
                                              const int* __restrict__ deg, const int* __restrict__ csrc,
                                              const float* __restrict__ dinv, const float* __restrict__ b2,
                                              int M, float* __restrict__ out) {
    int i = blockIdx.x * 256 + threadIdx.x;
    if (i >= M) return;
    int q = i / 12;
    int c = i - q * 12;
    int v = q * 15 + 3 + c;
    int start = rowptr[v];
    int cnt = deg[v];
    float s = zs[v];
    for (int j = 0; j < cnt; j++) s += zs[csrc[start + j]];  // zs 600KB -> L2 hits
    out[i] = fmaxf(fmaf(dinv[v], s, b2[0]), 0.f);
}

extern "C" void kernel_launch(void* const* d_in, const int* in_sizes, int n_in,
                              void* d_out, int out_size, void* d_ws, size_t ws_size,
                              hipStream_t stream) {
    const float* obs = (const float*)d_in[0];
    const int*   ei  = (const int*)d_in[1];   // [2,E]; JAX x64-off -> int32
    const float* W1  = (const float*)d_in[2];
    const float* b1  = (const float*)d_in[3];
    const float* W2  = (const float*)d_in[4];
    const float* b2  = (const float*)d_in[5];

    const int N = in_sizes[0] / 64;
    const int E = in_sizes[1] / 2;
    const int M = out_size;
    const int NB = (N + BK - 1) / BK;        // 586

    const int* src = ei;
    const int* dst = ei + E;

    // workspace layout
    ushort* Yh    = (ushort*)d_ws;             // N*64 bf16 (19.2 MB)
    float*  dinv  = (float*)(Yh + (size_t)N * 64);
    float*  zs    = dinv + N;
    int*    deg   = (int*)(zs + N);
    int*    rowptr= deg + N;
    int*    bcnt  = rowptr + N;                // NB
    int*    boff  = bcnt + NB;                 // NB+1
    int*    bcur  = boff + NB + 1;             // NB
    uint*   ebuf  = (uint*)(bcur + NB);        // E (4.8 MB)
    int*    csrc  = (int*)(ebuf + E);          // E (4.8 MB)

    hipMemsetAsync(deg, 0, (size_t)N * sizeof(int), stream);

    k_deg    <<<(E + 255) / 256, 256, 0, stream>>>(dst, E, deg);
    k_degsum <<<NB, 256, 0, stream>>>(deg, N, dinv, bcnt);
    k_bscan  <<<1, 1024, 0, stream>>>(bcnt, NB, boff, bcur);
    k_scan3  <<<NB, 256, 0, stream>>>(deg, boff, N, rowptr);
    k_bucket2<<<(E + EPB - 1) / EPB, 256, 0, stream>>>(src, dst, E, NB, bcur, ebuf);
    k_gemm1  <<<(N + 63) / 64, 256, 0, stream>>>(obs, W1, dinv, N, Yh);
    k_fill2  <<<NB, 256, 0, stream>>>(ebuf, boff, rowptr, N, csrc);
    k_agg    <<<((size_t)N * 16 + 255) / 256, 256, 0, stream>>>(Yh, rowptr, deg, csrc, dinv, b1, W2, N, zs);
    k_out2   <<<(M + 255) / 256, 256, 0, stream>>>(zs, rowptr, deg, csrc, dinv, b2, M, (float*)d_out);
}

// Round 6
// 125.460 us; speedup vs baseline: 7.6548x; 1.6149x over previous
//
#include <hip/hip_runtime.h>

// GCN 2-layer forward on MI355X — atomic-free clustered CSR build + 8-lane gather.
// N=150000, E=1.2M, IN=HID=64, layer-2 out dim = 1.
//
// pre1 = dinv[v]*(sum_{e:dst=v} Y[src] + Y[v]) + b1,  Y = (x@W1) row-scaled by dinv (bf16)
// zs   = (relu(pre1).W2) * dinv
// out  = relu(dinv[v]*(sum zs[src] + zs[v]) + b2), sliced v%15 in 3..14

#define BK 256        // nodes per bucket
#define NBMAX 640     // >= NB=586
#define EPB 8192      // edges per block for hist/place
#define HB 160        // padded per-bucket row length (>= nblk=147)

typedef unsigned int uint;
typedef unsigned short ushort;

static __device__ __forceinline__ ushort f2bf(float x) {
    uint u = __float_as_uint(x);
    u = (u + 0x7FFFu + ((u >> 16) & 1u)) >> 16;   // RN-even
    return (ushort)u;
}

// per-block LDS histogram of dst>>8 -> hist[j*HB + b]
__global__ __launch_bounds__(256) void k_hist(const int* __restrict__ dst, int E, int nb,
                                              int* __restrict__ hist) {
    __shared__ int h[NBMAX];
    const int t = threadIdx.x, b = blockIdx.x;
    for (int j = t; j < nb; j += 256) h[j] = 0;
    __syncthreads();
    const int e0 = b * EPB, e1 = min(e0 + EPB, E);
    for (int e = e0 + t; e < e1; e += 256) atomicAdd(&h[dst[e] >> 8], 1);
    __syncthreads();
    for (int j = t; j < nb; j += 256) hist[j * HB + b] = h[j];
}

// per bucket j: exclusive prefix over blocks (in place), column total -> colsum[j]
__global__ __launch_bounds__(256) void k_cscan1(int* __restrict__ hist, int nblk,
                                                int* __restrict__ colsum) {
    __shared__ int s[256];
    const int j = blockIdx.x, t = threadIdx.x;
    int v = (t < nblk) ? hist[j * HB + t] : 0;
    s[t] = v;
    __syncthreads();
    for (int o = 1; o < 256; o <<= 1) {
        int x = s[t];
        if (t >= o) x += s[t - o];
        __syncthreads();
        s[t] = x;
        __syncthreads();
    }
    if (t < nblk) hist[j * HB + t] = s[t] - v;
    if (t == 255) colsum[j] = s[t];
}

// single block: exclusive scan colsum[nb] -> boff[nb+1]; rowptr[N] = E
__global__ __launch_bounds__(1024) void k_cscan2(const int* __restrict__ colsum, int nb, int N,
                                                 int* __restrict__ boff, int* __restrict__ rowptr) {
    __shared__ int s[1024];
    const int t = threadIdx.x;
    int v = (t < nb) ? colsum[t] : 0;
    s[t] = v;
    __syncthreads();
    for (int o = 1; o < 1024; o <<= 1) {
        int x = s[t];
        if (t >= o) x += s[t - o];
        __syncthreads();
        s[t] = x;
        __syncthreads();
    }
    if (t < nb) boff[t] = s[t] - v;
    if (t == nb - 1) { boff[nb] = s[t]; rowptr[N] = s[t]; }
}

// place edges into per-(block,bucket) reserved chunks (clustered writes, LDS cursors)
__global__ __launch_bounds__(256) void k_place(const int* __restrict__ src, const int* __restrict__ dst,
                                               int E, int nb, const int* __restrict__ hist,
                                               const int* __restrict__ boff, uint* __restrict__ ebuf) {
    __shared__ int cur[NBMAX];
    const int t = threadIdx.x, b = blockIdx.x;
    for (int j = t; j < nb; j += 256) cur[j] = boff[j] + hist[j * HB + b];
    __syncthreads();
    const int e0 = b * EPB, e1 = min(e0 + EPB, E);
    for (int e = e0 + t; e < e1; e += 256) {
        int d = dst[e];
        int p = atomicAdd(&cur[d >> 8], 1);
        ebuf[p] = ((uint)(d & 255) << 24) | (uint)src[e];
    }
}

// per bucket: node histogram (=deg) -> dinv + rowptr (local scan) + csrc placement
__global__ __launch_bounds__(256) void k_fill3(const uint* __restrict__ ebuf, const int* __restrict__ boff,
                                               int N, int* __restrict__ rowptr, float* __restrict__ dinv,
                                               int* __restrict__ csrc) {
    __shared__ int cnt[BK];
    __shared__ int sc[BK];
    __shared__ int cur[BK];
    const int b = blockIdx.x, v0 = b << 8, t = threadIdx.x;
    const int nv = min(BK, N - v0);
    cnt[t] = 0;
    __syncthreads();
    const int bb = boff[b], be = boff[b + 1];
    for (int j = bb + t; j < be; j += 256) atomicAdd(&cnt[ebuf[j] >> 24], 1);
    __syncthreads();
    const int c = cnt[t];
    if (t < nv) dinv[v0 + t] = rsqrtf((float)c + 1.0f);
    sc[t] = c;
    __syncthreads();
    for (int o = 1; o < 256; o <<= 1) {
        int x = sc[t];
        if (t >= o) x += sc[t - o];
        __syncthreads();
        sc[t] = x;
        __syncthreads();
    }
    const int ex = sc[t] - c + bb;
    if (t < nv) rowptr[v0 + t] = ex;
    cur[t] = ex;
    __syncthreads();
    for (int j = bb + t; j < be; j += 256) {
        uint e = ebuf[j];
        int p = atomicAdd(&cur[e >> 24], 1);
        csrc[p] = (int)(e & 0xFFFFFFu);
    }
}

// X[N,64] @ W[64,64], row-scale by dinv -> Y (bf16)
__global__ __launch_bounds__(256) void k_gemm1(const float* __restrict__ X, const float* __restrict__ W,
                                               const float* __restrict__ dinv, int N,
                                               ushort* __restrict__ Yh) {
    __shared__ float Wl[64 * 64];
    __shared__ float Al[64 * 66];
    const int t = threadIdx.x;
    const int row0 = blockIdx.x * 64;
    {
        const float4* Wv = (const float4*)W;
        float4* Wlv = (float4*)Wl;
#pragma unroll
        for (int i = 0; i < 4; i++) Wlv[t + i * 256] = Wv[t + i * 256];
    }
    {
#pragma unroll
        for (int i = 0; i < 4; i++) {
            int f = t + i * 256;
            int r = f >> 4;
            int c4 = f & 15;
            int gr = row0 + r;
            float4 v = (gr < N) ? ((const float4*)X)[gr * 16 + c4] : make_float4(0.f, 0.f, 0.f, 0.f);
            float* dp = &Al[r * 66 + c4 * 4];
            dp[0] = v.x; dp[1] = v.y; dp[2] = v.z; dp[3] = v.w;
        }
    }
    __syncthreads();

    const int r = t & 63;
    const int cb = t >> 6;
    float acc[16];
#pragma unroll
    for (int j = 0; j < 16; j++) acc[j] = 0.f;
#pragma unroll 8
    for (int k = 0; k < 64; k++) {
        float a = Al[r * 66 + k];
#pragma unroll
        for (int j = 0; j < 16; j++)
            acc[j] = fmaf(a, Wl[k * 64 + cb * 16 + j], acc[j]);
    }
    int gr = row0 + r;
    if (gr < N) {
        float s = dinv[gr];
        ushort* op = Yh + (size_t)gr * 64 + cb * 16;
#pragma unroll
        for (int j = 0; j < 16; j += 4) {
            ushort4 o = make_ushort4(f2bf(acc[j] * s), f2bf(acc[j + 1] * s),
                                     f2bf(acc[j + 2] * s), f2bf(acc[j + 3] * s));
            ((ushort4*)(op + j))[0] = o;
        }
    }
}

// Fused layer-1 gather + bias/relu + dot(W2) + *dinv -> zs.
// 8 lanes per node; lane li owns features 8li..8li+7 (uint4 = 8 bf16).
// Indices loaded 8-wide coalesced, rows loaded with predicated unroll (ILP).
__global__ __launch_bounds__(256) void k_agg(const ushort* __restrict__ Yh, const int* __restrict__ rowptr,
                                             const int* __restrict__ csrc, const float* __restrict__ dinv,
                                             const float* __restrict__ b1, const float* __restrict__ W2,
                                             int N, float* __restrict__ zs) {
    int t = blockIdx.x * 256 + threadIdx.x;
    int v = t >> 3;
    if (v >= N) return;
    int li = t & 7;
    const uint4* Y4 = (const uint4*)Yh;
    int start = rowptr[v];
    int cnt = rowptr[v + 1] - start;

    float a[8];
    {
        uint4 m = Y4[(size_t)v * 8 + li];  // self-loop term
        a[0] = __uint_as_float(m.x << 16);
        a[1] = __uint_as_float(m.x & 0xFFFF0000u);
        a[2] = __uint_as_float(m.y << 16);
        a[3] = __uint_as_float(m.y & 0xFFFF0000u);
        a[4] = __uint_as_float(m.z << 16);
        a[5] = __uint_as_float(m.z & 0xFFFF0000u);
        a[6] = __uint_as_float(m.w << 16);
        a[7] = __uint_as_float(m.w & 0xFFFF0000u);
    }

    for (int j0 = 0; j0 < cnt; j0 += 8) {
        int rem = cnt - j0;
        int myidx = 0;
        if (li < rem) myidx = csrc[start + j0 + li];  // one coalesced 32B read per 8 edges
#pragma unroll
        for (int k = 0; k < 8; k++) {
            if (k < rem) {
                int s = __shfl(myidx, k, 8);
                uint4 m = Y4[(size_t)s * 8 + li];     // independent 16B loads -> ILP
                a[0] += __uint_as_float(m.x << 16);
                a[1] += __uint_as_float(m.x & 0xFFFF0000u);
                a[2] += __uint_as_float(m.y << 16);
                a[3] += __uint_as_float(m.y & 0xFFFF0000u);
                a[4] += __uint_as_float(m.z << 16);
                a[5] += __uint_as_float(m.z & 0xFFFF0000u);
                a[6] += __uint_as_float(m.w << 16);
                a[7] += __uint_as_float(m.w & 0xFFFF0000u);
            }
        }
    }

    float dv = dinv[v];
    float4 ba = ((const float4*)b1)[2 * li], bb = ((const float4*)b1)[2 * li + 1];
    float4 wa = ((const float4*)W2)[2 * li], wb = ((const float4*)W2)[2 * li + 1];
    float p;
    p  = fmaxf(fmaf(dv, a[0], ba.x), 0.f) * wa.x;
    p += fmaxf(fmaf(dv, a[1], ba.y), 0.f) * wa.y;
    p += fmaxf(fmaf(dv, a[2], ba.z), 0.f) * wa.z;
    p += fmaxf(fmaf(dv, a[3], ba.w), 0.f) * wa.w;
    p += fmaxf(fmaf(dv, a[4], bb.x), 0.f) * wb.x;
    p += fmaxf(fmaf(dv, a[5], bb.y), 0.f) * wb.y;
    p += fmaxf(fmaf(dv, a[6], bb.z), 0.f) * wb.z;
    p += fmaxf(fmaf(dv, a[7], bb.w), 0.f) * wb.w;
    p += __shfl_xor(p, 1);
    p += __shfl_xor(p, 2);
    p += __shfl_xor(p, 4);
    if (li == 0) zs[v] = p * dv;
}

// layer-2 scalar gather + output slice: v = (i/12)*15 + 3 + i%12
__global__ __launch_bounds__(256) void k_out2(const float* __restrict__ zs, const int* __restrict__ rowptr,
                                              const int* __restrict__ csrc, const float* __restrict__ dinv,
                                              const float* __restrict__ b2, int M, float* __restrict__ out) {
    int i = blockIdx.x * 256 + threadIdx.x;
    if (i >= M) return;
    int q = i / 12;
    int c = i - q * 12;
    int v = q * 15 + 3 + c;
    int j = rowptr[v];
    const int end = rowptr[v + 1];
    float s = zs[v];
    for (; j + 4 <= end; j += 4) {
        int i0 = csrc[j], i1 = csrc[j + 1], i2 = csrc[j + 2], i3 = csrc[j + 3];
        s += zs[i0] + zs[i1] + zs[i2] + zs[i3];   // 4 independent L2-hot loads
    }
    for (; j < end; j++) s += zs[csrc[j]];
    out[i] = fmaxf(fmaf(dinv[v], s, b2[0]), 0.f);
}

extern "C" void kernel_launch(void* const* d_in, const int* in_sizes, int n_in,
                              void* d_out, int out_size, void* d_ws, size_t ws_size,
                              hipStream_t stream) {
    const float* obs = (const float*)d_in[0];
    const int*   ei  = (const int*)d_in[1];   // [2,E]; JAX x64-off -> int32
    const float* W1  = (const float*)d_in[2];
    const float* b1  = (const float*)d_in[3];
    const float* W2  = (const float*)d_in[4];
    const float* b2  = (const float*)d_in[5];

    const int N = in_sizes[0] / 64;
    const int E = in_sizes[1] / 2;
    const int M = out_size;
    const int NB = (N + BK - 1) / BK;          // 586
    const int NBLK = (E + EPB - 1) / EPB;      // 147 (<= HB, <= 256)

    const int* src = ei;
    const int* dst = ei + E;

    // workspace layout
    ushort* Yh     = (ushort*)d_ws;                  // N*64 bf16 (19.2 MB)
    float*  dinv   = (float*)(Yh + (size_t)N * 64);  // N
    float*  zs     = dinv + N;                       // N
    int*    rowptr = (int*)(zs + N);                 // N+1
    int*    colsum = rowptr + N + 1;                 // NBMAX
    int*    boff   = colsum + NBMAX;                 // NBMAX+1
    int*    hist   = boff + NBMAX + 1;               // NBMAX*HB (410 KB)
    uint*   ebuf   = (uint*)(hist + NBMAX * HB);     // E (4.8 MB)
    int*    csrc   = (int*)(ebuf + E);               // E (4.8 MB)

    k_hist  <<<NBLK, 256, 0, stream>>>(dst, E, NB, hist);
    k_cscan1<<<NB, 256, 0, stream>>>(hist, NBLK, colsum);
    k_cscan2<<<1, 1024, 0, stream>>>(colsum, NB, N, boff, rowptr);
    k_place <<<NBLK, 256, 0, stream>>>(src, dst, E, NB, hist, boff, ebuf);
    k_fill3 <<<NB, 256, 0, stream>>>(ebuf, boff, N, rowptr, dinv, csrc);
    k_gemm1 <<<(N + 63) / 64, 256, 0, stream>>>(obs, W1, dinv, N, Yh);
    k_agg   <<<((size_t)N * 8 + 255) / 256, 256, 0, stream>>>(Yh, rowptr, csrc, dinv, b1, W2, N, zs);
    k_out2  <<<(M + 255) / 256, 256, 0, stream>>>(zs, rowptr, csrc, dinv, b2, M, (float*)d_out);
}

// Round 7
// 106.622 us; speedup vs baseline: 9.0073x; 1.1767x over previous
//
#include <hip/hip_runtime.h>

// GCN 2-layer forward on MI355X — atomic-free clustered CSR build + 8-lane gather
// + MFMA bf16 feature transform.
// N=150000, E=1.2M, IN=HID=64, layer-2 out dim = 1.
//
// pre1 = dinv[v]*(sum_{e:dst=v} Y[src] + Y[v]) + b1,  Y = (x@W1) row-scaled by dinv (bf16)
// zs   = (relu(pre1).W2) * dinv
// out  = relu(dinv[v]*(sum zs[src] + zs[v]) + b2), sliced v%15 in 3..14

#define BK 256        // nodes per bucket
#define NBMAX 640     // >= NB=586
#define EPB 8192      // edges per block for hist/place
#define HB 160        // padded per-bucket row length (>= nblk=147)

typedef unsigned int uint;
typedef unsigned short ushort;
typedef __attribute__((ext_vector_type(8))) short bf16x8_t;
typedef __attribute__((ext_vector_type(4))) float f32x4_t;

static __device__ __forceinline__ ushort f2bf(float x) {
    uint u = __float_as_uint(x);
    u = (u + 0x7FFFu + ((u >> 16) & 1u)) >> 16;   // RN-even
    return (ushort)u;
}

// per-block LDS histogram of dst>>8 -> hist[j*HB + b]
__global__ __launch_bounds__(256) void k_hist(const int* __restrict__ dst, int E, int nb,
                                              int* __restrict__ hist) {
    __shared__ int h[NBMAX];
    const int t = threadIdx.x, b = blockIdx.x;
    for (int j = t; j < nb; j += 256) h[j] = 0;
    __syncthreads();
    const int e0 = b * EPB, e1 = min(e0 + EPB, E);
    for (int e = e0 + t; e < e1; e += 256) atomicAdd(&h[dst[e] >> 8], 1);
    __syncthreads();
    for (int j = t; j < nb; j += 256) hist[j * HB + b] = h[j];
}

// per bucket j: exclusive prefix over blocks (in place), column total -> colsum[j]
__global__ __launch_bounds__(256) void k_cscan1(int* __restrict__ hist, int nblk,
                                                int* __restrict__ colsum) {
    __shared__ int s[256];
    const int j = blockIdx.x, t = threadIdx.x;
    int v = (t < nblk) ? hist[j * HB + t] : 0;
    s[t] = v;
    __syncthreads();
    for (int o = 1; o < 256; o <<= 1) {
        int x = s[t];
        if (t >= o) x += s[t - o];
        __syncthreads();
        s[t] = x;
        __syncthreads();
    }
    if (t < nblk) hist[j * HB + t] = s[t] - v;
    if (t == 255) colsum[j] = s[t];
}

// single block: exclusive scan colsum[nb] -> boff[nb+1]; rowptr[N] = E
__global__ __launch_bounds__(1024) void k_cscan2(const int* __restrict__ colsum, int nb, int N,
                                                 int* __restrict__ boff, int* __restrict__ rowptr) {
    __shared__ int s[1024];
    const int t = threadIdx.x;
    int v = (t < nb) ? colsum[t] : 0;
    s[t] = v;
    __syncthreads();
    for (int o = 1; o < 1024; o <<= 1) {
        int x = s[t];
        if (t >= o) x += s[t - o];
        __syncthreads();
        s[t] = x;
        __syncthreads();
    }
    if (t < nb) boff[t] = s[t] - v;
    if (t == nb - 1) { boff[nb] = s[t]; rowptr[N] = s[t]; }
}

// place edges into per-(block,bucket) reserved chunks (clustered writes, LDS cursors)
__global__ __launch_bounds__(256) void k_place(const int* __restrict__ src, const int* __restrict__ dst,
                                               int E, int nb, const int* __restrict__ hist,
                                               const int* __restrict__ boff, uint* __restrict__ ebuf) {
    __shared__ int cur[NBMAX];
    const int t = threadIdx.x, b = blockIdx.x;
    for (int j = t; j < nb; j += 256) cur[j] = boff[j] + hist[j * HB + b];
    __syncthreads();
    const int e0 = b * EPB, e1 = min(e0 + EPB, E);
    for (int e = e0 + t; e < e1; e += 256) {
        int d = dst[e];
        int p = atomicAdd(&cur[d >> 8], 1);
        ebuf[p] = ((uint)(d & 255) << 24) | (uint)src[e];
    }
}

// per bucket: node histogram (=deg) -> dinv + rowptr (local scan) + csrc placement
__global__ __launch_bounds__(256) void k_fill3(const uint* __restrict__ ebuf, const int* __restrict__ boff,
                                               int N, int* __restrict__ rowptr, float* __restrict__ dinv,
                                               int* __restrict__ csrc) {
    __shared__ int cnt[BK];
    __shared__ int sc[BK];
    __shared__ int cur[BK];
    const int b = blockIdx.x, v0 = b << 8, t = threadIdx.x;
    const int nv = min(BK, N - v0);
    cnt[t] = 0;
    __syncthreads();
    const int bb = boff[b], be = boff[b + 1];
    for (int j = bb + t; j < be; j += 256) atomicAdd(&cnt[ebuf[j] >> 24], 1);
    __syncthreads();
    const int c = cnt[t];
    if (t < nv) dinv[v0 + t] = rsqrtf((float)c + 1.0f);
    sc[t] = c;
    __syncthreads();
    for (int o = 1; o < 256; o <<= 1) {
        int x = sc[t];
        if (t >= o) x += sc[t - o];
        __syncthreads();
        sc[t] = x;
        __syncthreads();
    }
    const int ex = sc[t] - c + bb;
    if (t < nv) rowptr[v0 + t] = ex;
    cur[t] = ex;
    __syncthreads();
    for (int j = bb + t; j < be; j += 256) {
        uint e = ebuf[j];
        int p = atomicAdd(&cur[e >> 24], 1);
        csrc[p] = (int)(e & 0xFFFFFFu);
    }
}

// MFMA feature transform: Y = (X @ W1) * dinv, emitted bf16.
// Block = 256 threads = 4 waves; wave handles 16 rows; 8x mfma_f32_16x16x32_bf16.
// A-frags straight from global (each wave consumes 16 full 256B rows);
// W1 staged transposed-bf16 in LDS, stride 72 shorts (16B-aligned, <=2-way banks).
__global__ __launch_bounds__(256) void k_gemm1(const float* __restrict__ X, const float* __restrict__ W,
                                               const float* __restrict__ dinv, int N,
                                               ushort* __restrict__ Yh) {
    __shared__ __align__(16) ushort Wt[64 * 72];  // Wt[col][k]
    const int t = threadIdx.x;

    // stage W^T as bf16 (one-time, 4096 elems)
#pragma unroll
    for (int i = 0; i < 4; i++) {
        int idx = t + i * 256;          // float4 index, 0..1023
        int k = idx >> 4;
        int c4 = idx & 15;
        float4 w4 = ((const float4*)W)[idx];
        Wt[(c4 * 4 + 0) * 72 + k] = f2bf(w4.x);
        Wt[(c4 * 4 + 1) * 72 + k] = f2bf(w4.y);
        Wt[(c4 * 4 + 2) * 72 + k] = f2bf(w4.z);
        Wt[(c4 * 4 + 3) * 72 + k] = f2bf(w4.w);
    }
    __syncthreads();

    const int l = t & 63;
    const int lr = l & 15;                       // A-row / B-col within tile
    const int g = l >> 4;                        // k-group
    const int rw = blockIdx.x * 64 + (t >> 6) * 16;  // wave's row base

    // A fragments for the two K=32 steps (row = rw+lr, k = s*32 + g*8 + i)
    bf16x8_t afr[2];
#pragma unroll
    for (int s = 0; s < 2; s++) {
        const int row = rw + lr;
        float4 xa = make_float4(0.f, 0.f, 0.f, 0.f), xb = xa;
        if (row < N) {
            const float4* xp = (const float4*)(X + (size_t)row * 64 + s * 32 + g * 8);
            xa = xp[0];
            xb = xp[1];
        }
        bf16x8_t af;
        af[0] = (short)f2bf(xa.x); af[1] = (short)f2bf(xa.y);
        af[2] = (short)f2bf(xa.z); af[3] = (short)f2bf(xa.w);
        af[4] = (short)f2bf(xb.x); af[5] = (short)f2bf(xb.y);
        af[6] = (short)f2bf(xb.z); af[7] = (short)f2bf(xb.w);
        afr[s] = af;
    }

    // dinv for this lane's 4 C-rows (rw+4g..+3; workspace has slack past N, 16B aligned)
    const float4 dv = *(const float4*)(dinv + rw + g * 4);

#pragma unroll
    for (int c = 0; c < 4; c++) {
        f32x4_t acc = {0.f, 0.f, 0.f, 0.f};
#pragma unroll
        for (int s = 0; s < 2; s++) {
            const bf16x8_t bf = *(const bf16x8_t*)&Wt[(c * 16 + lr) * 72 + s * 32 + g * 8];
            acc = __builtin_amdgcn_mfma_f32_16x16x32_bf16(afr[s], bf, acc, 0, 0, 0);
        }
        const int col = c * 16 + lr;
#pragma unroll
        for (int r = 0; r < 4; r++) {
            const int row = rw + g * 4 + r;
            if (row < N) {
                const float sc = (r == 0) ? dv.x : (r == 1) ? dv.y : (r == 2) ? dv.z : dv.w;
                Yh[(size_t)row * 64 + col] = f2bf(acc[r] * sc);
            }
        }
    }
}

// Fused layer-1 gather + bias/relu + dot(W2) + *dinv -> zs.
// 8 lanes per node; lane li owns features 8li..8li+7 (uint4 = 8 bf16).
__global__ __launch_bounds__(256) void k_agg(const ushort* __restrict__ Yh, const int* __restrict__ rowptr,
                                             const int* __restrict__ csrc, const float* __restrict__ dinv,
                                             const float* __restrict__ b1, const float* __restrict__ W2,
                                             int N, float* __restrict__ zs) {
    int t = blockIdx.x * 256 + threadIdx.x;
    int v = t >> 3;
    if (v >= N) return;
    int li = t & 7;
    const uint4* Y4 = (const uint4*)Yh;
    int start = rowptr[v];
    int cnt = rowptr[v + 1] - start;

    float a[8];
    {
        uint4 m = Y4[(size_t)v * 8 + li];  // self-loop term
        a[0] = __uint_as_float(m.x << 16);
        a[1] = __uint_as_float(m.x & 0xFFFF0000u);
        a[2] = __uint_as_float(m.y << 16);
        a[3] = __uint_as_float(m.y & 0xFFFF0000u);
        a[4] = __uint_as_float(m.z << 16);
        a[5] = __uint_as_float(m.z & 0xFFFF0000u);
        a[6] = __uint_as_float(m.w << 16);
        a[7] = __uint_as_float(m.w & 0xFFFF0000u);
    }

    for (int j0 = 0; j0 < cnt; j0 += 8) {
        int rem = cnt - j0;
        int myidx = 0;
        if (li < rem) myidx = csrc[start + j0 + li];  // one coalesced 32B read per 8 edges
#pragma unroll
        for (int k = 0; k < 8; k++) {
            if (k < rem) {
                int s = __shfl(myidx, k, 8);
                uint4 m = Y4[(size_t)s * 8 + li];     // independent 16B loads -> ILP
                a[0] += __uint_as_float(m.x << 16);
                a[1] += __uint_as_float(m.x & 0xFFFF0000u);
                a[2] += __uint_as_float(m.y << 16);
                a[3] += __uint_as_float(m.y & 0xFFFF0000u);
                a[4] += __uint_as_float(m.z << 16);
                a[5] += __uint_as_float(m.z & 0xFFFF0000u);
                a[6] += __uint_as_float(m.w << 16);
                a[7] += __uint_as_float(m.w & 0xFFFF0000u);
            }
        }
    }

    float dv = dinv[v];
    float4 ba = ((const float4*)b1)[2 * li], bb = ((const float4*)b1)[2 * li + 1];
    float4 wa = ((const float4*)W2)[2 * li], wb = ((const float4*)W2)[2 * li + 1];
    float p;
    p  = fmaxf(fmaf(dv, a[0], ba.x), 0.f) * wa.x;
    p += fmaxf(fmaf(dv, a[1], ba.y), 0.f) * wa.y;
    p += fmaxf(fmaf(dv, a[2], ba.z), 0.f) * wa.z;
    p += fmaxf(fmaf(dv, a[3], ba.w), 0.f) * wa.w;
    p += fmaxf(fmaf(dv, a[4], bb.x), 0.f) * wb.x;
    p += fmaxf(fmaf(dv, a[5], bb.y), 0.f) * wb.y;
    p += fmaxf(fmaf(dv, a[6], bb.z), 0.f) * wb.z;
    p += fmaxf(fmaf(dv, a[7], bb.w), 0.f) * wb.w;
    p += __shfl_xor(p, 1);
    p += __shfl_xor(p, 2);
    p += __shfl_xor(p, 4);
    if (li == 0) zs[v] = p * dv;
}

// layer-2 scalar gather + output slice: v = (i/12)*15 + 3 + i%12
__global__ __launch_bounds__(256) void k_out2(const float* __restrict__ zs, const int* __restrict__ rowptr,
                                              const int* __restrict__ csrc, const float* __restrict__ dinv,
                                              const float* __restrict__ b2, int M, float* __restrict__ out) {
    int i = blockIdx.x * 256 + threadIdx.x;
    if (i >= M) return;
    int q = i / 12;
    int c = i - q * 12;
    int v = q * 15 + 3 + c;
    int j = rowptr[v];
    const int end = rowptr[v + 1];
    float s = zs[v];
    for (; j + 4 <= end; j += 4) {
        int i0 = csrc[j], i1 = csrc[j + 1], i2 = csrc[j + 2], i3 = csrc[j + 3];
        s += zs[i0] + zs[i1] + zs[i2] + zs[i3];   // 4 independent L2-hot loads
    }
    for (; j < end; j++) s += zs[csrc[j]];
    out[i] = fmaxf(fmaf(dinv[v], s, b2[0]), 0.f);
}

extern "C" void kernel_launch(void* const* d_in, const int* in_sizes, int n_in,
                              void* d_out, int out_size, void* d_ws, size_t ws_size,
                              hipStream_t stream) {
    const float* obs = (const float*)d_in[0];
    const int*   ei  = (const int*)d_in[1];   // [2,E]; JAX x64-off -> int32
    const float* W1  = (const float*)d_in[2];
    const float* b1  = (const float*)d_in[3];
    const float* W2  = (const float*)d_in[4];
    const float* b2  = (const float*)d_in[5];

    const int N = in_sizes[0] / 64;
    const int E = in_sizes[1] / 2;
    const int M = out_size;
    const int NB = (N + BK - 1) / BK;          // 586
    const int NBLK = (E + EPB - 1) / EPB;      // 147 (<= HB, <= 256)

    const int* src = ei;
    const int* dst = ei + E;

    // workspace layout
    ushort* Yh     = (ushort*)d_ws;                  // N*64 bf16 (19.2 MB)
    float*  dinv   = (float*)(Yh + (size_t)N * 64);  // N
    float*  zs     = dinv + N;                       // N
    int*    rowptr = (int*)(zs + N);                 // N+1
    int*    colsum = rowptr + N + 1;                 // NBMAX
    int*    boff   = colsum + NBMAX;                 // NBMAX+1
    int*    hist   = boff + NBMAX + 1;               // NBMAX*HB (410 KB)
    uint*   ebuf   = (uint*)(hist + NBMAX * HB);     // E (4.8 MB)
    int*    csrc   = (int*)(ebuf + E);               // E (4.8 MB)

    k_hist  <<<NBLK, 256, 0, stream>>>(dst, E, NB, hist);
    k_cscan1<<<NB, 256, 0, stream>>>(hist, NBLK, colsum);
    k_cscan2<<<1, 1024, 0, stream>>>(colsum, NB, N, boff, rowptr);
    k_place <<<NBLK, 256, 0, stream>>>(src, dst, E, NB, hist, boff, ebuf);
    k_fill3 <<<NB, 256, 0, stream>>>(ebuf, boff, N, rowptr, dinv, csrc);
    k_gemm1 <<<(N + 63) / 64, 256, 0, stream>>>(obs, W1, dinv, N, Yh);
    k_agg   <<<((size_t)N * 8 + 255) / 256, 256, 0, stream>>>(Yh, rowptr, csrc, dinv, b1, W2, N, zs);
    k_out2  <<<(M + 255) / 256, 256, 0, stream>>>(zs, rowptr, csrc, dinv, b2, M, (float*)d_out);
}